// Round 3
// baseline (211.421 us; speedup 1.0000x reference)
//
#include <hip/hip_runtime.h>

// Problem constants:
// inputs: (B=8, C=2, D=96, H=64, W=64) f32
// weight/bias: (F=8, C=2, d=3, h=60, w=64) f32
// out: (B=8, F=8, Dout=94, h=60, w=64) f32
#define B_ 8
#define C_ 2
#define D_ 96
#define H_ 64
#define W_ 64
#define F_ 8
#define KD 3
#define h_ 60
#define Dout_ 94
#define PLANE (h_ * W_)          // 3840 floats
#define NCH (PLANE / 4)          // 960 float4 chunks
#define TD 8                     // douts per block in k_main
#define NTILE ((Dout_ + TD - 1) / TD)  // 12
#define NS2 (B_ * C_ * D_)       // 1536 s2 planes
#define S2_FLOATS ((size_t)NS2 * PLANE)

// NOTE: was a macro FMA4(a,v,w) — the parameter `w` was substituted inside
// member accesses (`(a).w` -> `(a).wrA[...]`). Inline function is hygienic.
__device__ __forceinline__ void fma4(float4& a, const float4 v, const float4 g) {
    a.x += v.x * g.x; a.y += v.y * g.y;
    a.z += v.z * g.z; a.w += v.w * g.w;
}

// Horizontal 3-tap sum via lane shuffles; col4 = position 0..15 within a
// 16-lane row group. Boundary cols contribute zero.
__device__ __forceinline__ float4 hsum3(float4 V, int col4) {
    const int lane = threadIdx.x & 63;
    float lw = __shfl(V.w, (lane + 63) & 63, 64);
    float rx = __shfl(V.x, (lane + 1) & 63, 64);
    if (col4 == 0) lw = 0.f;
    if (col4 == 15) rx = 0.f;
    float4 o;
    o.x = lw + V.x + V.y;
    o.y = V.x + V.y + V.z;
    o.z = V.y + V.z + V.w;
    o.w = V.z + V.w + rx;
    return o;
}

// ---------------------------------------------------------------------------
// Fused prep kernel (unchanged from the proven R0 version).
// Blocks 0..NS2-1:            S2[b,c,p] = vertical 5-sum of input plane.
// Blocks NS2..NS2+F_-1:       BoxBS[f]  = Box3x3( sum_{c,z} bias[f,c,z] ).
// ---------------------------------------------------------------------------
__global__ __launch_bounds__(256) void k_prep(const float* __restrict__ in,
                                              const float* __restrict__ bs,
                                              float* __restrict__ s2,
                                              float* __restrict__ bb) {
    const int bx = blockIdx.x;
    const int tid = threadIdx.x;
    __shared__ float4 lds[H_ * 16];  // 16 KB (>= 62*16 used by bias path)

    if (bx < NS2) {
        const float4* ip4 = (const float4*)(in + (size_t)bx * (H_ * W_));
        float4* op4 = (float4*)(s2 + (size_t)bx * PLANE);
#pragma unroll
        for (int k = 0; k < 4; ++k) lds[tid + 256 * k] = ip4[tid + 256 * k];
        __syncthreads();
#pragma unroll
        for (int k = 0; k < 4; ++k) {
            const int e = tid + 256 * k;
            if (e < NCH) {
                const int row = e >> 4, col = e & 15;
                float4 s = lds[row * 16 + col];
#pragma unroll
                for (int j = 1; j < 5; ++j) {
                    const float4 v = lds[(row + j) * 16 + col];
                    s.x += v.x; s.y += v.y; s.z += v.z; s.w += v.w;
                }
                op4[e] = s;
            }
        }
    } else {
        const int f = bx - NS2;
        float4* R = lds;  // rows 0..61, row 0 and 61 zero
        if (tid < 32) {
            const int r = (tid >> 4) ? 61 : 0;
            R[r * 16 + (tid & 15)] = make_float4(0, 0, 0, 0);
        }
        const float4* bp = (const float4*)(bs + (size_t)f * (C_ * KD * PLANE));
#pragma unroll
        for (int k = 0; k < 4; ++k) {
            const int e = tid + 256 * k;
            if (e < NCH) {
                float4 s = make_float4(0, 0, 0, 0);
#pragma unroll
                for (int s6 = 0; s6 < 6; ++s6) {
                    const float4 v = bp[s6 * NCH + e];
                    s.x += v.x; s.y += v.y; s.z += v.z; s.w += v.w;
                }
                R[((e >> 4) + 1) * 16 + (e & 15)] = s;
            }
        }
        __syncthreads();
        float4* ob = (float4*)(bb + (size_t)f * PLANE);
#pragma unroll
        for (int k = 0; k < 4; ++k) {
            const int e = tid + 256 * k;
            if (e < NCH) {
                const int row = e >> 4, c4 = e & 15;
                const float4 a = R[row * 16 + c4];
                const float4 m = R[(row + 1) * 16 + c4];
                const float4 d = R[(row + 2) * 16 + c4];
                float4 V;
                V.x = a.x + m.x + d.x; V.y = a.y + m.y + d.y;
                V.z = a.z + m.z + d.z; V.w = a.w + m.w + d.w;
                ob[e] = hsum3(V, c4);
            }
        }
    }
}

// ---------------------------------------------------------------------------
// Main kernel (R3 == R2 design, compile-fixed).
//  * R0's proven linear mapping: thread t owns chunks e = t and t+512
//    (stride-512) -> fully coalesced global loads/stores, linear stride-16
//    LDS (e-indexed) -> zero bank conflicts. Plain stores (R1's NT stores
//    caused 1.66x write amplification).
//  * Rolling S2 register window over z: per c keep S2[p],S2[p+1] in regs and
//    load only S2[p+2] each dout -> 4 global loads/thread/dout (was 24).
//  * TD=8 amortizes weight/bias/window prologue over twice the douts.
//  * 512 threads: weight cache 12 float4 = 48 VGPR; __launch_bounds__(512,4)
//    = 2 blocks/CU = 16 waves/CU.
//  * XCD pin b = bx&7 (B_==8 XCDs): b's 2.95 MB S2 slice fits one XCD L2.
//  * Vertical 3-tap reuses own acc as middle row: 2 LDS reads per chunk.
// ---------------------------------------------------------------------------
__global__ __launch_bounds__(512, 4) void k_main(const float* __restrict__ s2,
                                                 const float* __restrict__ wt,
                                                 const float* __restrict__ bb,
                                                 float* __restrict__ out) {
    const int bx = blockIdx.x;
    const int b = bx & 7;            // XCD-pinned batch index
    const int f = (bx >> 3) & 7;
    const int tile = bx >> 6;        // 0..11
    const int d0 = tile * TD;
    const int t = threadIdx.x;
    const int eA = t;                // chunk A: rows 0..31
    const int eB = t + 512;          // chunk B: rows 32..63 (valid < NCH)
    const bool actB = (eB < NCH);    // t < 448
    const int col4 = t & 15;

    __shared__ float4 R[2][62 * 16]; // 31744 B, double-buffered, linear layout

    // zero pad rows (0 and 61) of both buffers
    if (t < 64) {
        const int buf = t >> 5;
        const int idx = t & 31;
        const int row = (idx >> 4) ? 61 : 0;
        R[buf][row * 16 + (idx & 15)] = make_float4(0, 0, 0, 0);
    }

    // loop-invariant register caches: weights (48 VGPR) + boxed bias (8 VGPR)
    const float4* wp = (const float4*)(wt + (size_t)f * (C_ * KD * PLANE));
    const float4* bbp = (const float4*)(bb + (size_t)f * PLANE);
    float4 wrA[6], wrB[6];
#pragma unroll
    for (int s6 = 0; s6 < 6; ++s6) {
        wrA[s6] = wp[s6 * NCH + eA];
        wrB[s6] = actB ? wp[s6 * NCH + eB] : make_float4(0, 0, 0, 0);
    }
    const float4 bbA = bbp[eA];
    const float4 bbB = actB ? bbp[eB] : make_float4(0, 0, 0, 0);

    const float4* s2b = (const float4*)s2 + (size_t)(b * C_) * D_ * NCH;
    float* ob = out + (size_t)((b * F_ + f) * Dout_) * PLANE;

    // rolling window: win[c][0] = S2[dout], win[c][1] = S2[dout+1]
    float4 winA[C_][2], winB[C_][2];
#pragma unroll
    for (int c = 0; c < C_; ++c) {
        const float4* sp0 = s2b + (size_t)(c * D_ + d0) * NCH;
        winA[c][0] = sp0[eA];
        winB[c][0] = actB ? sp0[eB] : make_float4(0, 0, 0, 0);
        winA[c][1] = sp0[NCH + eA];
        winB[c][1] = actB ? sp0[NCH + eB] : make_float4(0, 0, 0, 0);
    }

#pragma unroll
    for (int td = 0; td < TD; ++td) {
        const int dout = d0 + td;
        int p2 = dout + 2;
        if (p2 > D_ - 1) p2 = D_ - 1;  // only hits for discarded tail douts

        // the ONE new plane per c this dout
        float4 nA[C_], nB[C_];
#pragma unroll
        for (int c = 0; c < C_; ++c) {
            const float4* sp = s2b + (size_t)(c * D_ + p2) * NCH;
            nA[c] = sp[eA];
            nB[c] = actB ? sp[eB] : make_float4(0, 0, 0, 0);
        }

        // acc = sum_{c,z} S2[dout+z] .* wt[c,z]  (same summation order as R0)
        float4 aA = make_float4(0, 0, 0, 0);
        float4 aB = make_float4(0, 0, 0, 0);
#pragma unroll
        for (int c = 0; c < C_; ++c) {
            fma4(aA, winA[c][0], wrA[c * 3 + 0]);
            fma4(aA, winA[c][1], wrA[c * 3 + 1]);
            fma4(aA, nA[c],      wrA[c * 3 + 2]);
            fma4(aB, winB[c][0], wrB[c * 3 + 0]);
            fma4(aB, winB[c][1], wrB[c * 3 + 1]);
            fma4(aB, nB[c],      wrB[c * 3 + 2]);
        }

        // rotate window (static indices, fully unrolled -> pure renaming)
#pragma unroll
        for (int c = 0; c < C_; ++c) {
            winA[c][0] = winA[c][1]; winA[c][1] = nA[c];
            winB[c][0] = winB[c][1]; winB[c][1] = nB[c];
        }

        // vertical staging: linear layout, Rb[e + 16] == row (e>>4)+1, col e&15
        float4* Rb = R[td & 1];
        Rb[eA + 16] = aA;
        if (actB) Rb[eB + 16] = aB;
        __syncthreads();   // single barrier per dout (dbuf prevents WAR)

        if (dout < Dout_) {
            float4* od4 = (float4*)(ob + (size_t)dout * PLANE);

            // chunk A: rows r-1 (LDS), r (own acc), r+1 (LDS)
            {
                const float4 u = Rb[eA];
                const float4 dn = Rb[eA + 32];
                float4 V;
                V.x = u.x + aA.x + dn.x; V.y = u.y + aA.y + dn.y;
                V.z = u.z + aA.z + dn.z; V.w = u.w + aA.w + dn.w;
                float4 o = hsum3(V, col4);
                o.x = 0.25f * (o.x + bbA.x); o.y = 0.25f * (o.y + bbA.y);
                o.z = 0.25f * (o.z + bbA.z); o.w = 0.25f * (o.w + bbA.w);
                o.x = (o.x > 0.f) ? o.x : 0.2f * o.x;
                o.y = (o.y > 0.f) ? o.y : 0.2f * o.y;
                o.z = (o.z > 0.f) ? o.z : 0.2f * o.z;
                o.w = (o.w > 0.f) ? o.w : 0.2f * o.w;
                od4[eA] = o;
            }
            // chunk B
            if (actB) {
                const float4 u = Rb[eB];
                const float4 dn = Rb[eB + 32];
                float4 V;
                V.x = u.x + aB.x + dn.x; V.y = u.y + aB.y + dn.y;
                V.z = u.z + aB.z + dn.z; V.w = u.w + aB.w + dn.w;
                float4 o = hsum3(V, col4);
                o.x = 0.25f * (o.x + bbB.x); o.y = 0.25f * (o.y + bbB.y);
                o.z = 0.25f * (o.z + bbB.z); o.w = 0.25f * (o.w + bbB.w);
                o.x = (o.x > 0.f) ? o.x : 0.2f * o.x;
                o.y = (o.y > 0.f) ? o.y : 0.2f * o.y;
                o.z = (o.z > 0.f) ? o.z : 0.2f * o.z;
                o.w = (o.w > 0.f) ? o.w : 0.2f * o.w;
                od4[eB] = o;
            }
        }
    }
}

extern "C" void kernel_launch(void* const* d_in, const int* in_sizes, int n_in,
                              void* d_out, int out_size, void* d_ws, size_t ws_size,
                              hipStream_t stream) {
    const float* in = (const float*)d_in[0];
    const float* wt = (const float*)d_in[1];
    const float* bs = (const float*)d_in[2];
    float* out = (float*)d_out;

    float* s2 = (float*)d_ws;
    float* bb = s2 + S2_FLOATS;

    k_prep<<<dim3(NS2 + F_), dim3(256), 0, stream>>>(in, bs, s2, bb);
    k_main<<<dim3(B_ * F_ * NTILE), dim3(512), 0, stream>>>(s2, wt, bb, out);
}

// Round 4
// 143.836 us; speedup vs baseline: 1.4699x; 1.4699x over previous
//
#include <hip/hip_runtime.h>

// Problem constants:
// inputs: (B=8, C=2, D=96, H=64, W=64) f32
// weight/bias: (F=8, C=2, d=3, h=60, w=64) f32
// out: (B=8, F=8, Dout=94, h=60, w=64) f32
#define B_ 8
#define C_ 2
#define D_ 96
#define H_ 64
#define W_ 64
#define F_ 8
#define KD 3
#define h_ 60
#define Dout_ 94
#define PLANE (h_ * W_)          // 3840 floats
#define NCH (PLANE / 4)          // 960 float4 chunks
#define TD 4                     // douts batched per block (ONE barrier per batch)
#define NTILE ((Dout_ + TD - 1) / TD)  // 24
#define NS2 (B_ * C_ * D_)       // 1536 s2 planes
#define S2_FLOATS ((size_t)NS2 * PLANE)

__device__ __forceinline__ void fma4(float4& a, const float4 v, const float4 g) {
    a.x += v.x * g.x; a.y += v.y * g.y;
    a.z += v.z * g.z; a.w += v.w * g.w;
}

// Horizontal 3-tap sum via lane shuffles; col4 = position 0..15 within a
// 16-lane row group. Boundary cols contribute zero. All 64 lanes must execute.
__device__ __forceinline__ float4 hsum3(float4 V, int col4) {
    const int lane = threadIdx.x & 63;
    float lw = __shfl(V.w, (lane + 63) & 63, 64);
    float rx = __shfl(V.x, (lane + 1) & 63, 64);
    if (col4 == 0) lw = 0.f;
    if (col4 == 15) rx = 0.f;
    float4 o;
    o.x = lw + V.x + V.y;
    o.y = V.x + V.y + V.z;
    o.z = V.y + V.z + V.w;
    o.w = V.z + V.w + rx;
    return o;
}

// ---------------------------------------------------------------------------
// Fused prep kernel (unchanged, proven).
// Blocks 0..NS2-1:            S2[b,c,p] = vertical 5-sum of input plane.
// Blocks NS2..NS2+F_-1:       BoxBS[f]  = Box3x3( sum_{c,z} bias[f,c,z] ).
// ---------------------------------------------------------------------------
__global__ __launch_bounds__(256) void k_prep(const float* __restrict__ in,
                                              const float* __restrict__ bs,
                                              float* __restrict__ s2,
                                              float* __restrict__ bb) {
    const int bx = blockIdx.x;
    const int tid = threadIdx.x;
    __shared__ float4 lds[H_ * 16];  // 16 KB

    if (bx < NS2) {
        const float4* ip4 = (const float4*)(in + (size_t)bx * (H_ * W_));
        float4* op4 = (float4*)(s2 + (size_t)bx * PLANE);
#pragma unroll
        for (int k = 0; k < 4; ++k) lds[tid + 256 * k] = ip4[tid + 256 * k];
        __syncthreads();
#pragma unroll
        for (int k = 0; k < 4; ++k) {
            const int e = tid + 256 * k;
            if (e < NCH) {
                const int row = e >> 4, col = e & 15;
                float4 s = lds[row * 16 + col];
#pragma unroll
                for (int j = 1; j < 5; ++j) {
                    const float4 v = lds[(row + j) * 16 + col];
                    s.x += v.x; s.y += v.y; s.z += v.z; s.w += v.w;
                }
                op4[e] = s;
            }
        }
    } else {
        const int f = bx - NS2;
        float4* R = lds;  // rows 0..61, rows 0 and 61 zero
        if (tid < 32) {
            const int r = (tid >> 4) ? 61 : 0;
            R[r * 16 + (tid & 15)] = make_float4(0, 0, 0, 0);
        }
        const float4* bp = (const float4*)(bs + (size_t)f * (C_ * KD * PLANE));
#pragma unroll
        for (int k = 0; k < 4; ++k) {
            const int e = tid + 256 * k;
            if (e < NCH) {
                float4 s = make_float4(0, 0, 0, 0);
#pragma unroll
                for (int s6 = 0; s6 < 6; ++s6) {
                    const float4 v = bp[s6 * NCH + e];
                    s.x += v.x; s.y += v.y; s.z += v.z; s.w += v.w;
                }
                R[((e >> 4) + 1) * 16 + (e & 15)] = s;
            }
        }
        __syncthreads();
        float4* ob = (float4*)(bb + (size_t)f * PLANE);
#pragma unroll
        for (int k = 0; k < 4; ++k) {
            const int e = tid + 256 * k;
            if (e < NCH) {
                const int row = e >> 4, c4 = e & 15;
                const float4 a = R[row * 16 + c4];
                const float4 m = R[(row + 1) * 16 + c4];
                const float4 d = R[(row + 2) * 16 + c4];
                float4 V;
                V.x = a.x + m.x + d.x; V.y = a.y + m.y + d.y;
                V.z = a.z + m.z + d.z; V.w = a.w + m.w + d.w;
                ob[e] = hsum3(V, c4);
            }
        }
    }
}

// ---------------------------------------------------------------------------
// Main kernel (R4): half-plane blocks + batched barrier.
//  * Block = (b, f, tile, half). Each half owns 30 output rows and computes
//    32 acc rows (1-row halo each side, ~6.7% redundant FMA) -> blocks are
//    fully independent; no inter-block row sharing.
//  * 256 threads, 2 chunks/thread (rows lr and lr+16 of the 32-row slab).
//    Weight cache = 12 float4 = 48 regs. __launch_bounds__(256,4): 128-reg
//    cap (safe vs ~100 est; R3's spill came from 48 extra window regs).
//  * Phase 1: all TD=4 douts' acc -> LDS, NO barriers between (48 loads of
//    deep MLP). ONE __syncthreads. Phase 2: all 4 epilogues + stores.
//    Barrier drains: 1 per block (was 4). 4 independent blocks/CU (was 3).
//  * LDS = TD x 512 x 16B = 32 KB, linear indexing (measured-0-conflict
//    pattern). Plain coalesced stores. XCD pin b = bx&7.
// ---------------------------------------------------------------------------
__global__ __launch_bounds__(256, 4) void k_main(const float* __restrict__ s2,
                                                 const float* __restrict__ wt,
                                                 const float* __restrict__ bb,
                                                 float* __restrict__ out) {
    const int bx = blockIdx.x;
    const int b = bx & 7;            // XCD-pinned batch index
    const int f = (bx >> 3) & 7;
    const int half = (bx >> 6) & 1;
    const int tile = bx >> 7;        // 0..23
    const int d0 = tile * TD;
    const int t = threadIdx.x;
    const int col4 = t & 15;
    const int lr = t >> 4;           // local row 0..15

    // global acc rows: chunk A = gbase+lr, chunk B = gbase+lr+16
    const int gbase = half * 30 - 1;      // -1 or 29
    const int gA = gbase + lr;            // [-1..45]
    const int gB = gA + 16;               // [15..60]
    const bool vA = (gA >= 0) && (gA <= 59);
    const bool vB = (gB >= 0) && (gB <= 59);
    const int cgA = min(max(gA, 0), h_ - 1);
    const int cgB = min(max(gB, 0), h_ - 1);
    const int eA = cgA * 16 + col4;       // clamped plane chunk index
    const int eB = cgB * 16 + col4;

    __shared__ float4 Lds[TD][512];       // 32 KB

    // loop-invariant caches: weights 12 float4 (48 regs) + boxed bias (8 regs)
    const float4* wp = (const float4*)(wt + (size_t)f * (C_ * KD * PLANE));
    const float4* bbp = (const float4*)(bb + (size_t)f * PLANE);
    float4 wrA[6], wrB[6];
#pragma unroll
    for (int s6 = 0; s6 < 6; ++s6) {
        wrA[s6] = wp[s6 * NCH + eA];
        wrB[s6] = wp[s6 * NCH + eB];
    }
    const float4 bbA = bbp[eA];
    const float4 bbB = bbp[eB];

    const float4* s2b = (const float4*)s2 + (size_t)(b * C_) * D_ * NCH;
    float* ob = out + (size_t)((b * F_ + f) * Dout_) * PLANE;

    // ---- phase 1: TD accs, no intermediate barriers ----
#pragma unroll
    for (int td = 0; td < TD; ++td) {
        float4 aA = make_float4(0, 0, 0, 0);
        float4 aB = make_float4(0, 0, 0, 0);
#pragma unroll
        for (int c = 0; c < C_; ++c)
#pragma unroll
            for (int z = 0; z < KD; ++z) {
                int p = d0 + td + z;
                if (p > D_ - 1) p = D_ - 1;  // only for discarded tail douts
                const float4* sp = s2b + (size_t)(c * D_ + p) * NCH;
                fma4(aA, sp[eA], wrA[c * KD + z]);
                fma4(aB, sp[eB], wrB[c * KD + z]);
            }
        if (!vA) aA = make_float4(0, 0, 0, 0);   // halo pad rows are zero
        if (!vB) aB = make_float4(0, 0, 0, 0);
        Lds[td][t] = aA;          // local chunk A = lr*16+col4 = t
        Lds[td][t + 256] = aB;    // local chunk B
    }
    __syncthreads();   // the ONE barrier per block

    // ---- phase 2: TD epilogues ----
    const bool sA = (lr >= 1);                 // owns output row gA
    const bool sB = (lr <= 14);                // owns output row gB
    const int iuA = (lr == 0) ? t : t - 16;    // clamp (discarded anyway)
    const int idB = (lr == 15) ? t + 256 : t + 272;
    const int oA = gA * 16 + col4;
    const int oB = gB * 16 + col4;

#pragma unroll
    for (int td = 0; td < TD; ++td) {
        const int dout = d0 + td;

        // chunk A vertical 3-tap
        const float4 uA = Lds[td][iuA];
        const float4 mA = Lds[td][t];
        const float4 dA = Lds[td][t + 16];     // lr=15 -> chunk B row 16: valid
        float4 VA;
        VA.x = uA.x + mA.x + dA.x; VA.y = uA.y + mA.y + dA.y;
        VA.z = uA.z + mA.z + dA.z; VA.w = uA.w + mA.w + dA.w;
        float4 rA = hsum3(VA, col4);

        // chunk B vertical 3-tap
        const float4 uB = Lds[td][t + 240];    // chunk A row lr+15: valid
        const float4 mB = Lds[td][t + 256];
        const float4 dB = Lds[td][idB];
        float4 VB;
        VB.x = uB.x + mB.x + dB.x; VB.y = uB.y + mB.y + dB.y;
        VB.z = uB.z + mB.z + dB.z; VB.w = uB.w + mB.w + dB.w;
        float4 rB = hsum3(VB, col4);

        rA.x = 0.25f * (rA.x + bbA.x); rA.y = 0.25f * (rA.y + bbA.y);
        rA.z = 0.25f * (rA.z + bbA.z); rA.w = 0.25f * (rA.w + bbA.w);
        rB.x = 0.25f * (rB.x + bbB.x); rB.y = 0.25f * (rB.y + bbB.y);
        rB.z = 0.25f * (rB.z + bbB.z); rB.w = 0.25f * (rB.w + bbB.w);
        rA.x = (rA.x > 0.f) ? rA.x : 0.2f * rA.x;
        rA.y = (rA.y > 0.f) ? rA.y : 0.2f * rA.y;
        rA.z = (rA.z > 0.f) ? rA.z : 0.2f * rA.z;
        rA.w = (rA.w > 0.f) ? rA.w : 0.2f * rA.w;
        rB.x = (rB.x > 0.f) ? rB.x : 0.2f * rB.x;
        rB.y = (rB.y > 0.f) ? rB.y : 0.2f * rB.y;
        rB.z = (rB.z > 0.f) ? rB.z : 0.2f * rB.z;
        rB.w = (rB.w > 0.f) ? rB.w : 0.2f * rB.w;

        if (dout < Dout_) {
            float4* od4 = (float4*)(ob + (size_t)dout * PLANE);
            if (sA) od4[oA] = rA;
            if (sB) od4[oB] = rB;
        }
    }
}

extern "C" void kernel_launch(void* const* d_in, const int* in_sizes, int n_in,
                              void* d_out, int out_size, void* d_ws, size_t ws_size,
                              hipStream_t stream) {
    const float* in = (const float*)d_in[0];
    const float* wt = (const float*)d_in[1];
    const float* bs = (const float*)d_in[2];
    float* out = (float*)d_out;

    float* s2 = (float*)d_ws;
    float* bb = s2 + S2_FLOATS;

    k_prep<<<dim3(NS2 + F_), dim3(256), 0, stream>>>(in, bs, s2, bb);
    k_main<<<dim3(B_ * F_ * NTILE * 2), dim3(256), 0, stream>>>(s2, wt, bb, out);
}